// Round 8
// baseline (296.948 us; speedup 1.0000x reference)
//
#include <hip/hip_runtime.h>
#include <hip/hip_bf16.h>
#include <math.h>

typedef __attribute__((ext_vector_type(8))) short short8;
typedef __attribute__((ext_vector_type(4))) float f32x4;

__device__ inline unsigned short f2bf(float f) {
    unsigned int u = __float_as_uint(f);
    unsigned int r = u + 0x7fffu + ((u >> 16) & 1u);   // RTNE
    return (unsigned short)(r >> 16);
}
__device__ inline float bf2f(unsigned short h) {
    return __uint_as_float(((unsigned int)h) << 16);
}

// ---------------- fused prep: convX (hi/lo) + convW1 (hi) + convW2 (hi) + degree count ----------------

__global__ void prep_kernel(const float* __restrict__ x,
                            unsigned short* __restrict__ Xh, unsigned short* __restrict__ Xl,
                            const float* __restrict__ W1, unsigned short* __restrict__ W1hT,
                            const float* __restrict__ W2, unsigned short* __restrict__ W2hT,
                            const int* __restrict__ dst, int* __restrict__ deg,
                            int M, int K1, int Kp1, int H, int E,
                            int bX, int bW1, int bW2)
{
    const int b = blockIdx.x;
    const int tid = threadIdx.x;
    if (b < bX) {
        int id = b * 256 + tid;
        if (id < M * Kp1) {
            int r = id / Kp1;
            int k = id - r * Kp1;
            float v = (k < K1) ? x[(size_t)r * K1 + k] : 0.f;
            unsigned short h = f2bf(v);
            Xh[id] = h;
            Xl[id] = f2bf(v - bf2f(h));
        }
    } else if (b < bX + bW1) {
        int id = (b - bX) * 256 + tid;
        if (id < H * Kp1) {
            int nrow = id / Kp1;
            int k = id - nrow * Kp1;
            float v = (k < K1) ? W1[(size_t)k * H + nrow] : 0.f;
            W1hT[id] = f2bf(v);
        }
    } else if (b < bX + bW1 + bW2) {
        int id = (b - bX - bW1) * 256 + tid;
        if (id < H * H) {
            int nrow = id / H;
            int k = id - nrow * H;
            W2hT[id] = f2bf(W2[(size_t)k * H + nrow]);
        }
    } else {
        int e = (b - bX - bW1 - bW2) * 256 + tid;
        if (e < E) atomicAdd(&deg[dst[e]], 1);
    }
}

// ---------------- one-block scan (1024 threads) -> row_start; also dinv ----------------

__global__ __launch_bounds__(1024) void scan_kernel(const int* __restrict__ deg,
                                                    int* __restrict__ row_start,
                                                    float* __restrict__ dinv, int n)
{
    __shared__ int swave[16];
    __shared__ int s_run;
    const int lane = threadIdx.x & 63;
    const int w = threadIdx.x >> 6;
    if (threadIdx.x == 0) s_run = 0;
    __syncthreads();

    for (int base = 0; base < n; base += 1024) {
        int i = base + threadIdx.x;
        int v = (i < n) ? deg[i] : 0;
        int incl = v;
#pragma unroll
        for (int off = 1; off < 64; off <<= 1) {
            int t = __shfl_up(incl, off);
            if (lane >= off) incl += t;
        }
        if (lane == 63) swave[w] = incl;
        __syncthreads();
        int wpre = 0, total = 0;
#pragma unroll
        for (int j = 0; j < 16; j++) {
            int sv = swave[j];
            if (j < w) wpre += sv;
            total += sv;
        }
        int run = s_run;
        if (i < n) {
            row_start[i] = run + wpre + incl - v;
            dinv[i] = rsqrtf((float)v + 1.0f);
        }
        __syncthreads();
        if (threadIdx.x == 0) s_run = run + total;
        __syncthreads();
    }
    if (threadIdx.x == 0) row_start[n] = s_run;
}

// ---------------- CSR fill ----------------

__global__ void fill_csr_kernel(const int* __restrict__ src, const int* __restrict__ dst,
                                const int* __restrict__ row_start, int* __restrict__ cursor,
                                int* __restrict__ csr_src, int E)
{
    int e = blockIdx.x * blockDim.x + threadIdx.x;
    if (e >= E) return;
    int d = dst[e];
    int pos = row_start[d] + atomicAdd(&cursor[d], 1);
    csr_src[pos] = src[e];
}

// ---------------- LDS-free MFMA GEMM: Hb[M,N](bf16) = (Ah+Al) @ Wh ----------------
// 2-term split: Ah*Bh + Al*Bh (A exact, W bf16-rounded).
// Block = 128 threads (2 waves); tile 128x64; wave = 64(m) x 64(n).
// No LDS, no barriers: fragments loaded straight from global (L2-resident),
// register-double-buffered so iteration k+1's loads overlap iteration k's MFMAs.
// XCD swizzle: blocks with equal j%8 share the A row-tile on one XCD's L2.

#define TBK 32

__global__ __launch_bounds__(128, 2) void gemm_mfma_kernel(
    const unsigned short* __restrict__ AhG, const unsigned short* __restrict__ AlG,
    const unsigned short* __restrict__ WhT,
    unsigned short* __restrict__ Hb, int M, int N, int Kp, int tiles_m)
{
    const int j = blockIdx.x;
    const int tn = (j >> 3) & 7;
    const int tm = (j >> 6) * 8 + (j & 7);
    if (tm >= tiles_m) return;

    const int wave = threadIdx.x >> 6;
    const int lane = threadIdx.x & 63;
    const int quad = lane >> 4;
    const int l16  = lane & 15;

    const int row0 = tm * 128 + wave * 64;
    const int col0 = tn * 64;

    // per-lane fragment base pointers (A: m=l16 row, k=quad*8; B^T: n=l16 row, k=quad*8)
    const unsigned short* pAh[4];
    const unsigned short* pAl[4];
#pragma unroll
    for (int b = 0; b < 4; b++) {
        int r = row0 + b * 16 + l16;
        if (r >= M) r = M - 1;            // clamp: rows >= M computed but never stored
        size_t off = (size_t)r * Kp + quad * 8;
        pAh[b] = AhG + off;
        pAl[b] = AlG + off;
    }
    const unsigned short* pB[4];
#pragma unroll
    for (int ct = 0; ct < 4; ct++) {
        pB[ct] = WhT + (size_t)(col0 + ct * 16 + l16) * Kp + quad * 8;
    }

    f32x4 acc[4][4];
#pragma unroll
    for (int b = 0; b < 4; b++)
#pragma unroll
        for (int c = 0; c < 4; c++) acc[b][c] = (f32x4){0.f, 0.f, 0.f, 0.f};

    // prologue: load k=0 fragments
    short8 cAh[4], cAl[4], cB[4];
#pragma unroll
    for (int b = 0; b < 4; b++) {
        cAh[b] = *(const short8*)pAh[b];
        cAl[b] = *(const short8*)pAl[b];
    }
#pragma unroll
    for (int ct = 0; ct < 4; ct++) cB[ct] = *(const short8*)pB[ct];

#pragma unroll 2
    for (int k0 = TBK; k0 < Kp; k0 += TBK) {
        short8 nAh[4], nAl[4], nB[4];
#pragma unroll
        for (int b = 0; b < 4; b++) {
            nAh[b] = *(const short8*)(pAh[b] + k0);
            nAl[b] = *(const short8*)(pAl[b] + k0);
        }
#pragma unroll
        for (int ct = 0; ct < 4; ct++) nB[ct] = *(const short8*)(pB[ct] + k0);

#pragma unroll
        for (int ct = 0; ct < 4; ct++)
#pragma unroll
            for (int b = 0; b < 4; b++) {
                acc[b][ct] = __builtin_amdgcn_mfma_f32_16x16x32_bf16(cAh[b], cB[ct], acc[b][ct], 0, 0, 0);
                acc[b][ct] = __builtin_amdgcn_mfma_f32_16x16x32_bf16(cAl[b], cB[ct], acc[b][ct], 0, 0, 0);
            }
#pragma unroll
        for (int b = 0; b < 4; b++) { cAh[b] = nAh[b]; cAl[b] = nAl[b]; }
#pragma unroll
        for (int ct = 0; ct < 4; ct++) cB[ct] = nB[ct];
    }
    // epilogue MFMAs on final fragments
#pragma unroll
    for (int ct = 0; ct < 4; ct++)
#pragma unroll
        for (int b = 0; b < 4; b++) {
            acc[b][ct] = __builtin_amdgcn_mfma_f32_16x16x32_bf16(cAh[b], cB[ct], acc[b][ct], 0, 0, 0);
            acc[b][ct] = __builtin_amdgcn_mfma_f32_16x16x32_bf16(cAl[b], cB[ct], acc[b][ct], 0, 0, 0);
        }

    // store: C/D layout col=l16, row=quad*4+reg
#pragma unroll
    for (int b = 0; b < 4; b++) {
#pragma unroll
        for (int ct = 0; ct < 4; ct++) {
            int gc = col0 + ct * 16 + l16;
#pragma unroll
            for (int r = 0; r < 4; r++) {
                int gr = row0 + b * 16 + quad * 4 + r;
                if (gr < M) Hb[(size_t)gr * N + gc] = f2bf(acc[b][ct][r]);
            }
        }
    }
}

// ---------------- gather aggregation, F=512, bf16 input; emits relu'd hi/lo bf16 planes ----------------

#define GMAX 1024

__global__ __launch_bounds__(256) void gather512_kernel(
    const unsigned short* __restrict__ hb,
    unsigned short* __restrict__ out_h, unsigned short* __restrict__ out_l,
    const int* __restrict__ csr_src, const int* __restrict__ row_start,
    const float* __restrict__ dinv, const float* __restrict__ bias, int n)
{
    __shared__ int   s_idx[GMAX];
    __shared__ float s_w[GMAX];
    __shared__ float s_part[512];

    const int node = blockIdx.x;
    const int tid = threadIdx.x;
    const int half = tid >> 7;
    const int slot = tid & 127;
    const float di = dinv[node];

    const int beg = row_start[node], end = row_start[node + 1];

    float4 acc = make_float4(0.f, 0.f, 0.f, 0.f);

    for (int c0 = beg; c0 < end; c0 += GMAX) {
        int cnt = min(end - c0, GMAX);
        for (int p = tid; p < cnt; p += 256) {
            int s = csr_src[c0 + p];
            s_idx[p] = s;
            s_w[p] = dinv[s] * di;
        }
        __syncthreads();
        for (int p = half; p < cnt; p += 2) {
            int s = s_idx[p];
            float w = s_w[p];
            ushort4 r = *(const ushort4*)&hb[(size_t)s * 512 + slot * 4];
            acc.x += w * bf2f(r.x);
            acc.y += w * bf2f(r.y);
            acc.z += w * bf2f(r.z);
            acc.w += w * bf2f(r.w);
        }
        __syncthreads();
    }

    if (half == 1) *(float4*)&s_part[slot * 4] = acc;
    __syncthreads();
    if (half == 0) {
        float4 o = *(const float4*)&s_part[slot * 4];
        ushort4 rs = *(const ushort4*)&hb[(size_t)node * 512 + slot * 4];
        float4 b4 = *(const float4*)&bias[slot * 4];
        float dd = di * di;
        float vx = fmaxf(acc.x + o.x + dd * bf2f(rs.x) + b4.x, 0.f);
        float vy = fmaxf(acc.y + o.y + dd * bf2f(rs.y) + b4.y, 0.f);
        float vz = fmaxf(acc.z + o.z + dd * bf2f(rs.z) + b4.z, 0.f);
        float vw = fmaxf(acc.w + o.w + dd * bf2f(rs.w) + b4.w, 0.f);
        ushort4 ho, lo;
        ho.x = f2bf(vx); lo.x = f2bf(vx - bf2f(ho.x));
        ho.y = f2bf(vy); lo.y = f2bf(vy - bf2f(ho.y));
        ho.z = f2bf(vz); lo.z = f2bf(vz - bf2f(ho.z));
        ho.w = f2bf(vw); lo.w = f2bf(vw - bf2f(ho.w));
        const size_t ob = (size_t)node * 512 + slot * 4;
        *(ushort4*)&out_h[ob] = ho;
        *(ushort4*)&out_l[ob] = lo;
    }
}

// ---------------- small GEMM: h3[M,10] = A[M,512] @ Wc, A = hi/lo bf16 planes ----------------

__global__ __launch_bounds__(256) void gemm_small_kernel(
    const unsigned short* __restrict__ Ahp, const unsigned short* __restrict__ Alp,
    const float* __restrict__ W, float* __restrict__ C, int M, int K)
{
    __shared__ float Ws[512 * 10];
    for (int i = threadIdx.x; i < K * 10; i += blockDim.x) Ws[i] = W[i];
    __syncthreads();

    const int wave = threadIdx.x >> 6;
    const int lane = threadIdx.x & 63;
    const int row = blockIdx.x * (blockDim.x >> 6) + wave;
    if (row >= M) return;

    float acc[10];
#pragma unroll
    for (int c = 0; c < 10; c++) acc[c] = 0.f;

    for (int k = lane; k < K; k += 64) {
        float a = bf2f(Ahp[(size_t)row * K + k]) + bf2f(Alp[(size_t)row * K + k]);
#pragma unroll
        for (int c = 0; c < 10; c++) acc[c] += a * Ws[k * 10 + c];
    }
#pragma unroll
    for (int c = 0; c < 10; c++) {
#pragma unroll
        for (int off = 32; off; off >>= 1) acc[c] += __shfl_down(acc[c], off);
    }
    if (lane == 0) {
#pragma unroll
        for (int c = 0; c < 10; c++) C[(size_t)row * 10 + c] = acc[c];
    }
}

// ---------------- fused gather(F=10) + log_softmax ----------------

__global__ __launch_bounds__(256) void gather10_softmax_kernel(
    const float* __restrict__ h3, float* __restrict__ out,
    const int* __restrict__ csr_src, const int* __restrict__ row_start,
    const float* __restrict__ dinv, const float* __restrict__ bc, int n)
{
    const int wv = threadIdx.x >> 6;
    const int lane = threadIdx.x & 63;
    const int g = lane / 10;
    const int c = lane - g * 10;
    const int node = blockIdx.x * 24 + wv * 6 + g;
    const bool active = (lane < 60) && (node < n);

    float acc = 0.f;
    if (active) {
        float di = dinv[node];
        acc = h3[(size_t)node * 10 + c] * di * di + bc[c];
        int beg = row_start[node], end = row_start[node + 1];
        for (int p = beg; p < end; ++p) {
            int s = csr_src[p];
            acc += h3[(size_t)s * 10 + c] * dinv[s] * di;
        }
    }
    const int base = g * 10;
    float vj[10];
#pragma unroll
    for (int j = 0; j < 10; j++) vj[j] = __shfl(acc, base + j);
    if (active) {
        float m = vj[0];
#pragma unroll
        for (int j = 1; j < 10; j++) m = fmaxf(m, vj[j]);
        float ssum = 0.f;
#pragma unroll
        for (int j = 0; j < 10; j++) ssum += __expf(vj[j] - m);
        out[(size_t)node * 10 + c] = acc - (m + __logf(ssum));
    }
}

// ---------------- launch ----------------

extern "C" void kernel_launch(void* const* d_in, const int* in_sizes, int n_in,
                              void* d_out, int out_size, void* d_ws, size_t ws_size,
                              hipStream_t stream)
{
    const float* x   = (const float*)d_in[0];
    const int*   ei  = (const int*)d_in[1];
    const float* W1  = (const float*)d_in[2];
    const float* b1  = (const float*)d_in[3];
    const float* W2  = (const float*)d_in[4];
    const float* b2  = (const float*)d_in[5];
    const float* Wc  = (const float*)d_in[6];
    const float* bc  = (const float*)d_in[7];
    float* out = (float*)d_out;

    const int IN_FEATS = 784;
    const int KP1 = 800;
    const int H = 512;
    const int NC = 10;
    const int n = in_sizes[0] / IN_FEATS;   // 10000
    const int E = in_sizes[1] / 2;          // 160000
    const int* src = ei;
    const int* dst = ei + E;

    // workspace layout (~64 MB)
    char* ws = (char*)d_ws;
    unsigned short* Hb   = (unsigned short*)ws; ws += (size_t)n * H * sizeof(unsigned short);
    unsigned short* Xh   = (unsigned short*)ws; ws += (size_t)n * KP1 * sizeof(unsigned short);
    unsigned short* Xl   = (unsigned short*)ws; ws += (size_t)n * KP1 * sizeof(unsigned short);
    unsigned short* AhB  = (unsigned short*)ws; ws += (size_t)n * H * sizeof(unsigned short);
    unsigned short* AlB  = (unsigned short*)ws; ws += (size_t)n * H * sizeof(unsigned short);
    unsigned short* W1hT = (unsigned short*)ws; ws += (size_t)KP1 * H * sizeof(unsigned short);
    unsigned short* W2hT = (unsigned short*)ws; ws += (size_t)H * H * sizeof(unsigned short);
    float* dinv      = (float*)ws;             ws += (size_t)n * sizeof(float);
    int*   deg       = (int*)ws;               ws += (size_t)n * sizeof(int);
    int*   cursor    = (int*)ws;               ws += (size_t)n * sizeof(int);
    int*   csr_src   = (int*)ws;               ws += (size_t)E * sizeof(int);
    int*   row_start = (int*)ws;               ws += (size_t)(n + 1) * sizeof(int);
    float* h3        = (float*)ws;             ws += (size_t)n * NC * sizeof(float);

    hipMemsetAsync(deg, 0, (size_t)n * sizeof(int), stream);
    hipMemsetAsync(cursor, 0, (size_t)n * sizeof(int), stream);

    // ---- fused prep ----
    const int bX  = ((size_t)n * KP1 + 255) / 256;
    const int bW1 = (H * KP1 + 255) / 256;
    const int bW2 = (H * H + 255) / 256;
    const int bE  = (E + 255) / 256;
    prep_kernel<<<bX + bW1 + bW2 + bE, 256, 0, stream>>>(
        x, Xh, Xl, W1, W1hT, W2, W2hT, dst, deg,
        n, IN_FEATS, KP1, H, E, bX, bW1, bW2);

    scan_kernel<<<1, 1024, 0, stream>>>(deg, row_start, dinv, n);
    fill_csr_kernel<<<(E + 255) / 256, 256, 0, stream>>>(src, dst, row_start, cursor, csr_src, E);

    const int tiles_m = (n + 127) / 128;                    // 79
    const int gemm_grid = ((tiles_m + 7) / 8) * 64;         // 640 (8 early-exit)

    // ---- layer 1 ----
    gemm_mfma_kernel<<<gemm_grid, 128, 0, stream>>>(Xh, Xl, W1hT, Hb, n, H, KP1, tiles_m);
    gather512_kernel<<<n, 256, 0, stream>>>(Hb, AhB, AlB, csr_src, row_start, dinv, b1, n);

    // ---- layer 2 ----
    gemm_mfma_kernel<<<gemm_grid, 128, 0, stream>>>(AhB, AlB, W2hT, Hb, n, H, H, tiles_m);
    gather512_kernel<<<n, 256, 0, stream>>>(Hb, AhB, AlB, csr_src, row_start, dinv, b2, n);

    // ---- layer 3 + softmax ----
    gemm_small_kernel<<<(n + 3) / 4, 256, 0, stream>>>(AhB, AlB, Wc, h3, n, H);
    gather10_softmax_kernel<<<(n + 23) / 24, 256, 0, stream>>>(h3, out, csr_src, row_start, dinv, bc, n);
}

// Round 9
// 275.100 us; speedup vs baseline: 1.0794x; 1.0794x over previous
//
#include <hip/hip_runtime.h>
#include <hip/hip_bf16.h>
#include <math.h>

typedef __attribute__((ext_vector_type(8))) short short8;
typedef __attribute__((ext_vector_type(4))) float f32x4;

__device__ inline unsigned short f2bf(float f) {
    unsigned int u = __float_as_uint(f);
    unsigned int r = u + 0x7fffu + ((u >> 16) & 1u);   // RTNE
    return (unsigned short)(r >> 16);
}
__device__ inline float bf2f(unsigned short h) {
    return __uint_as_float(((unsigned int)h) << 16);
}

// async global->LDS, 16 B per lane; LDS dest = wave-uniform base + lane*16
__device__ __forceinline__ void gld16(const unsigned short* g, unsigned short* l) {
    __builtin_amdgcn_global_load_lds(
        (const __attribute__((address_space(1))) unsigned int*)g,
        (__attribute__((address_space(3))) unsigned int*)l, 16, 0, 0);
}

// ---------------- fused prep: convX (hi/lo) + convW1 (hi) + convW2 (hi) + degree count ----------------

__global__ void prep_kernel(const float* __restrict__ x,
                            unsigned short* __restrict__ Xh, unsigned short* __restrict__ Xl,
                            const float* __restrict__ W1, unsigned short* __restrict__ W1hT,
                            const float* __restrict__ W2, unsigned short* __restrict__ W2hT,
                            const int* __restrict__ dst, int* __restrict__ deg,
                            int M, int K1, int Kp1, int H, int E,
                            int bX, int bW1, int bW2)
{
    const int b = blockIdx.x;
    const int tid = threadIdx.x;
    if (b < bX) {
        int id = b * 256 + tid;
        if (id < M * Kp1) {
            int r = id / Kp1;
            int k = id - r * Kp1;
            float v = (k < K1) ? x[(size_t)r * K1 + k] : 0.f;
            unsigned short h = f2bf(v);
            Xh[id] = h;
            Xl[id] = f2bf(v - bf2f(h));
        }
    } else if (b < bX + bW1) {
        int id = (b - bX) * 256 + tid;
        if (id < H * Kp1) {
            int nrow = id / Kp1;
            int k = id - nrow * Kp1;
            float v = (k < K1) ? W1[(size_t)k * H + nrow] : 0.f;
            W1hT[id] = f2bf(v);
        }
    } else if (b < bX + bW1 + bW2) {
        int id = (b - bX - bW1) * 256 + tid;
        if (id < H * H) {
            int nrow = id / H;
            int k = id - nrow * H;
            W2hT[id] = f2bf(W2[(size_t)k * H + nrow]);
        }
    } else {
        int e = (b - bX - bW1 - bW2) * 256 + tid;
        if (e < E) atomicAdd(&deg[dst[e]], 1);
    }
}

// ---------------- one-block scan (1024 threads) -> row_start + cursor; also dinv ----------------

__global__ __launch_bounds__(1024) void scan_kernel(const int* __restrict__ deg,
                                                    int* __restrict__ row_start,
                                                    int* __restrict__ cursor,
                                                    float* __restrict__ dinv, int n)
{
    __shared__ int swave[16];
    __shared__ int s_run;
    const int lane = threadIdx.x & 63;
    const int w = threadIdx.x >> 6;
    if (threadIdx.x == 0) s_run = 0;
    __syncthreads();

    for (int base = 0; base < n; base += 1024) {
        int i = base + threadIdx.x;
        int v = (i < n) ? deg[i] : 0;
        int incl = v;
#pragma unroll
        for (int off = 1; off < 64; off <<= 1) {
            int t = __shfl_up(incl, off);
            if (lane >= off) incl += t;
        }
        if (lane == 63) swave[w] = incl;
        __syncthreads();
        int wpre = 0, total = 0;
#pragma unroll
        for (int j = 0; j < 16; j++) {
            int sv = swave[j];
            if (j < w) wpre += sv;
            total += sv;
        }
        int run = s_run;
        if (i < n) {
            int rs = run + wpre + incl - v;
            row_start[i] = rs;
            cursor[i] = rs;                 // fill_csr uses absolute cursor
            dinv[i] = rsqrtf((float)v + 1.0f);
        }
        __syncthreads();
        if (threadIdx.x == 0) s_run = run + total;
        __syncthreads();
    }
    if (threadIdx.x == 0) row_start[n] = s_run;
}

// ---------------- CSR fill (absolute cursor) ----------------

__global__ void fill_csr_kernel(const int* __restrict__ src, const int* __restrict__ dst,
                                int* __restrict__ cursor, int* __restrict__ csr_src, int E)
{
    int e = blockIdx.x * blockDim.x + threadIdx.x;
    if (e >= E) return;
    int d = dst[e];
    int pos = atomicAdd(&cursor[d], 1);
    csr_src[pos] = src[e];
}

// ---------------- MFMA GEMM: Hb[M,N](bf16) = (Ah+Al) @ Wh, 2-term split ----------------
// Tile 128x64, BK=32, 256 threads (4 waves, 2x2 wave grid).
// Staging via global_load_lds width=16 (async, no VGPR round-trip), unpadded 64 B LDS rows.
// XCD swizzle: blocks with equal j%8 share the A row-tile on one XCD's L2.

#define TBK 32

__global__ __launch_bounds__(256) void gemm_mfma_kernel(
    const unsigned short* __restrict__ AhG, const unsigned short* __restrict__ AlG,
    const unsigned short* __restrict__ WhT,
    unsigned short* __restrict__ Hb, int M, int N, int Kp, int tiles_m)
{
    const int j = blockIdx.x;
    const int tn = (j >> 3) & 7;
    const int tm = (j >> 6) * 8 + (j & 7);
    if (tm >= tiles_m) return;

    __shared__ unsigned short Ah[128 * TBK];   // rows of 64 B, contiguous
    __shared__ unsigned short Al[128 * TBK];
    __shared__ unsigned short Bh[64 * TBK];

    const int tid  = threadIdx.x;
    const int wave = tid >> 6;
    const int lane = tid & 63;
    const int quad = lane >> 4;
    const int l16  = lane & 15;
    const int row0 = tm * 128;
    const int col0 = tn * 64;
    const int rh = (wave & 1) * 64;      // wave row-half (64 rows)
    const int ch = (wave >> 1) * 32;     // wave col-half (32 cols)

    // ---- staging addresses (lane i: row i>>2, k-chunk (i&3)*8 -> LDS byte 16*i) ----
    const int srow = lane >> 2;          // 0..15
    const int skc  = (lane & 3) * 8;     // 0,8,16,24
    int ga0 = row0 + wave * 32 + srow;        if (ga0 >= M) ga0 = M - 1;
    int ga1 = row0 + wave * 32 + 16 + srow;   if (ga1 >= M) ga1 = M - 1;
    const unsigned short* gAh0 = AhG + (size_t)ga0 * Kp + skc;
    const unsigned short* gAh1 = AhG + (size_t)ga1 * Kp + skc;
    const unsigned short* gAl0 = AlG + (size_t)ga0 * Kp + skc;
    const unsigned short* gAl1 = AlG + (size_t)ga1 * Kp + skc;
    const unsigned short* gB   = WhT + (size_t)(col0 + wave * 16 + srow) * Kp + skc;
    unsigned short* lAh0 = &Ah[(wave * 32) * TBK];        // wave-uniform bases
    unsigned short* lAh1 = &Ah[(wave * 32 + 16) * TBK];
    unsigned short* lAl0 = &Al[(wave * 32) * TBK];
    unsigned short* lAl1 = &Al[(wave * 32 + 16) * TBK];
    unsigned short* lB   = &Bh[(wave * 16) * TBK];

    f32x4 acc[4][2];
#pragma unroll
    for (int b = 0; b < 4; b++)
#pragma unroll
        for (int c = 0; c < 2; c++) acc[b][c] = (f32x4){0.f, 0.f, 0.f, 0.f};

    for (int k0 = 0; k0 < Kp; k0 += TBK) {
        // ---- async stage: 5 x 1 KB per wave ----
        gld16(gAh0 + k0, lAh0);
        gld16(gAh1 + k0, lAh1);
        gld16(gAl0 + k0, lAl0);
        gld16(gAl1 + k0, lAl1);
        gld16(gB   + k0, lB);
        __syncthreads();   // compiler emits vmcnt(0) drain before barrier

        // ---- fragments + MFMA: 4 m-frags x 2 n-frags x 2 terms = 16 MFMA/wave ----
        short8 ah[4], al[4];
#pragma unroll
        for (int b = 0; b < 4; b++) {
            int off = (rh + b * 16 + l16) * TBK + quad * 8;
            ah[b] = *(const short8*)&Ah[off];
            al[b] = *(const short8*)&Al[off];
        }
#pragma unroll
        for (int ct = 0; ct < 2; ct++) {
            int off = (ch + ct * 16 + l16) * TBK + quad * 8;
            short8 bh = *(const short8*)&Bh[off];
#pragma unroll
            for (int b = 0; b < 4; b++) {
                acc[b][ct] = __builtin_amdgcn_mfma_f32_16x16x32_bf16(ah[b], bh, acc[b][ct], 0, 0, 0);
                acc[b][ct] = __builtin_amdgcn_mfma_f32_16x16x32_bf16(al[b], bh, acc[b][ct], 0, 0, 0);
            }
        }
        __syncthreads();
    }

    // ---- epilogue: C/D layout col=lane&15, row=quad*4+reg; bf16 store ----
#pragma unroll
    for (int b = 0; b < 4; b++) {
#pragma unroll
        for (int ct = 0; ct < 2; ct++) {
            int gc = col0 + ch + ct * 16 + l16;
#pragma unroll
            for (int r = 0; r < 4; r++) {
                int gr = row0 + rh + b * 16 + quad * 4 + r;
                if (gr < M) Hb[(size_t)gr * N + gc] = f2bf(acc[b][ct][r]);
            }
        }
    }
}

// ---------------- gather aggregation, F=512, bf16 input; emits relu'd hi/lo bf16 planes ----------------

#define GMAX 1024

__global__ __launch_bounds__(256) void gather512_kernel(
    const unsigned short* __restrict__ hb,
    unsigned short* __restrict__ out_h, unsigned short* __restrict__ out_l,
    const int* __restrict__ csr_src, const int* __restrict__ row_start,
    const float* __restrict__ dinv, const float* __restrict__ bias, int n)
{
    __shared__ int   s_idx[GMAX];
    __shared__ float s_w[GMAX];
    __shared__ float s_part[512];

    const int node = blockIdx.x;
    const int tid = threadIdx.x;
    const int half = tid >> 7;
    const int slot = tid & 127;
    const float di = dinv[node];

    const int beg = row_start[node], end = row_start[node + 1];

    float4 acc = make_float4(0.f, 0.f, 0.f, 0.f);

    for (int c0 = beg; c0 < end; c0 += GMAX) {
        int cnt = min(end - c0, GMAX);
        for (int p = tid; p < cnt; p += 256) {
            int s = csr_src[c0 + p];
            s_idx[p] = s;
            s_w[p] = dinv[s] * di;
        }
        __syncthreads();
        for (int p = half; p < cnt; p += 2) {
            int s = s_idx[p];
            float w = s_w[p];
            ushort4 r = *(const ushort4*)&hb[(size_t)s * 512 + slot * 4];
            acc.x += w * bf2f(r.x);
            acc.y += w * bf2f(r.y);
            acc.z += w * bf2f(r.z);
            acc.w += w * bf2f(r.w);
        }
        __syncthreads();
    }

    if (half == 1) *(float4*)&s_part[slot * 4] = acc;
    __syncthreads();
    if (half == 0) {
        float4 o = *(const float4*)&s_part[slot * 4];
        ushort4 rs = *(const ushort4*)&hb[(size_t)node * 512 + slot * 4];
        float4 b4 = *(const float4*)&bias[slot * 4];
        float dd = di * di;
        float vx = fmaxf(acc.x + o.x + dd * bf2f(rs.x) + b4.x, 0.f);
        float vy = fmaxf(acc.y + o.y + dd * bf2f(rs.y) + b4.y, 0.f);
        float vz = fmaxf(acc.z + o.z + dd * bf2f(rs.z) + b4.z, 0.f);
        float vw = fmaxf(acc.w + o.w + dd * bf2f(rs.w) + b4.w, 0.f);
        ushort4 ho, lo;
        ho.x = f2bf(vx); lo.x = f2bf(vx - bf2f(ho.x));
        ho.y = f2bf(vy); lo.y = f2bf(vy - bf2f(ho.y));
        ho.z = f2bf(vz); lo.z = f2bf(vz - bf2f(ho.z));
        ho.w = f2bf(vw); lo.w = f2bf(vw - bf2f(ho.w));
        const size_t ob = (size_t)node * 512 + slot * 4;
        *(ushort4*)&out_h[ob] = ho;
        *(ushort4*)&out_l[ob] = lo;
    }
}

// ---------------- small GEMM: h3[M,10] = A[M,512] @ Wc, A = hi/lo bf16 planes ----------------

__global__ __launch_bounds__(256) void gemm_small_kernel(
    const unsigned short* __restrict__ Ahp, const unsigned short* __restrict__ Alp,
    const float* __restrict__ W, float* __restrict__ C, int M, int K)
{
    __shared__ float Ws[512 * 10];
    for (int i = threadIdx.x; i < K * 10; i += blockDim.x) Ws[i] = W[i];
    __syncthreads();

    const int wave = threadIdx.x >> 6;
    const int lane = threadIdx.x & 63;
    const int row = blockIdx.x * (blockDim.x >> 6) + wave;
    if (row >= M) return;

    float acc[10];
#pragma unroll
    for (int c = 0; c < 10; c++) acc[c] = 0.f;

    for (int k = lane; k < K; k += 64) {
        float a = bf2f(Ahp[(size_t)row * K + k]) + bf2f(Alp[(size_t)row * K + k]);
#pragma unroll
        for (int c = 0; c < 10; c++) acc[c] += a * Ws[k * 10 + c];
    }
#pragma unroll
    for (int c = 0; c < 10; c++) {
#pragma unroll
        for (int off = 32; off; off >>= 1) acc[c] += __shfl_down(acc[c], off);
    }
    if (lane == 0) {
#pragma unroll
        for (int c = 0; c < 10; c++) C[(size_t)row * 10 + c] = acc[c];
    }
}

// ---------------- fused gather(F=10) + log_softmax ----------------

__global__ __launch_bounds__(256) void gather10_softmax_kernel(
    const float* __restrict__ h3, float* __restrict__ out,
    const int* __restrict__ csr_src, const int* __restrict__ row_start,
    const float* __restrict__ dinv, const float* __restrict__ bc, int n)
{
    const int wv = threadIdx.x >> 6;
    const int lane = threadIdx.x & 63;
    const int g = lane / 10;
    const int c = lane - g * 10;
    const int node = blockIdx.x * 24 + wv * 6 + g;
    const bool active = (lane < 60) && (node < n);

    float acc = 0.f;
    if (active) {
        float di = dinv[node];
        acc = h3[(size_t)node * 10 + c] * di * di + bc[c];
        int beg = row_start[node], end = row_start[node + 1];
        for (int p = beg; p < end; ++p) {
            int s = csr_src[p];
            acc += h3[(size_t)s * 10 + c] * dinv[s] * di;
        }
    }
    const int base = g * 10;
    float vj[10];
#pragma unroll
    for (int j = 0; j < 10; j++) vj[j] = __shfl(acc, base + j);
    if (active) {
        float m = vj[0];
#pragma unroll
        for (int j = 1; j < 10; j++) m = fmaxf(m, vj[j]);
        float ssum = 0.f;
#pragma unroll
        for (int j = 0; j < 10; j++) ssum += __expf(vj[j] - m);
        out[(size_t)node * 10 + c] = acc - (m + __logf(ssum));
    }
}

// ---------------- launch ----------------

extern "C" void kernel_launch(void* const* d_in, const int* in_sizes, int n_in,
                              void* d_out, int out_size, void* d_ws, size_t ws_size,
                              hipStream_t stream)
{
    const float* x   = (const float*)d_in[0];
    const int*   ei  = (const int*)d_in[1];
    const float* W1  = (const float*)d_in[2];
    const float* b1  = (const float*)d_in[3];
    const float* W2  = (const float*)d_in[4];
    const float* b2  = (const float*)d_in[5];
    const float* Wc  = (const float*)d_in[6];
    const float* bc  = (const float*)d_in[7];
    float* out = (float*)d_out;

    const int IN_FEATS = 784;
    const int KP1 = 800;
    const int H = 512;
    const int NC = 10;
    const int n = in_sizes[0] / IN_FEATS;   // 10000
    const int E = in_sizes[1] / 2;          // 160000
    const int* src = ei;
    const int* dst = ei + E;

    // workspace layout (~64 MB)
    char* ws = (char*)d_ws;
    unsigned short* Hb   = (unsigned short*)ws; ws += (size_t)n * H * sizeof(unsigned short);
    unsigned short* Xh   = (unsigned short*)ws; ws += (size_t)n * KP1 * sizeof(unsigned short);
    unsigned short* Xl   = (unsigned short*)ws; ws += (size_t)n * KP1 * sizeof(unsigned short);
    unsigned short* AhB  = (unsigned short*)ws; ws += (size_t)n * H * sizeof(unsigned short);
    unsigned short* AlB  = (unsigned short*)ws; ws += (size_t)n * H * sizeof(unsigned short);
    unsigned short* W1hT = (unsigned short*)ws; ws += (size_t)KP1 * H * sizeof(unsigned short);
    unsigned short* W2hT = (unsigned short*)ws; ws += (size_t)H * H * sizeof(unsigned short);
    float* dinv      = (float*)ws;             ws += (size_t)n * sizeof(float);
    int*   deg       = (int*)ws;               ws += (size_t)n * sizeof(int);
    int*   cursor    = (int*)ws;               ws += (size_t)n * sizeof(int);
    int*   csr_src   = (int*)ws;               ws += (size_t)E * sizeof(int);
    int*   row_start = (int*)ws;               ws += (size_t)(n + 1) * sizeof(int);
    float* h3        = (float*)ws;             ws += (size_t)n * NC * sizeof(float);

    hipMemsetAsync(deg, 0, (size_t)n * sizeof(int), stream);

    // ---- fused prep ----
    const int bX  = ((size_t)n * KP1 + 255) / 256;
    const int bW1 = (H * KP1 + 255) / 256;
    const int bW2 = (H * H + 255) / 256;
    const int bE  = (E + 255) / 256;
    prep_kernel<<<bX + bW1 + bW2 + bE, 256, 0, stream>>>(
        x, Xh, Xl, W1, W1hT, W2, W2hT, dst, deg,
        n, IN_FEATS, KP1, H, E, bX, bW1, bW2);

    scan_kernel<<<1, 1024, 0, stream>>>(deg, row_start, cursor, dinv, n);
    fill_csr_kernel<<<(E + 255) / 256, 256, 0, stream>>>(src, dst, cursor, csr_src, E);

    const int tiles_m = (n + 127) / 128;                    // 79
    const int gemm_grid = ((tiles_m + 7) / 8) * 64;         // 640 (8 early-exit)

    // ---- layer 1 ----
    gemm_mfma_kernel<<<gemm_grid, 256, 0, stream>>>(Xh, Xl, W1hT, Hb, n, H, KP1, tiles_m);
    gather512_kernel<<<n, 256, 0, stream>>>(Hb, AhB, AlB, csr_src, row_start, dinv, b1, n);

    // ---- layer 2 ----
    gemm_mfma_kernel<<<gemm_grid, 256, 0, stream>>>(AhB, AlB, W2hT, Hb, n, H, H, tiles_m);
    gather512_kernel<<<n, 256, 0, stream>>>(Hb, AhB, AlB, csr_src, row_start, dinv, b2, n);

    // ---- layer 3 + softmax ----
    gemm_small_kernel<<<(n + 3) / 4, 256, 0, stream>>>(AhB, AlB, Wc, h3, n, H);
    gather10_softmax_kernel<<<(n + 23) / 24, 256, 0, stream>>>(h3, out, csr_src, row_start, dinv, bc, n);
}